// Round 4
// baseline (537.653 us; speedup 1.0000x reference)
//
#include <hip/hip_runtime.h>
#include <hip/hip_bf16.h>

// VoxelEncoding: trilinear interpolation of 8 corner embeddings per point.
// Layout: 4 lanes per point; lane q of point n handles output dims [4q,4q+4).
// Each lane issues 8 independent float4 gathers (one per corner) -> full MLP,
// and 4 consecutive lanes cover one 64-B embedding row -> intra-row coalescing.

typedef float v4f __attribute__((ext_vector_type(4)));

__global__ __launch_bounds__(256) void VoxelEncoding_kernel(
    const float* __restrict__ pts,   // (N,3) f32
    const int*   __restrict__ p2v,   // (N,)  i32
    const float* __restrict__ emb,   // (N_EMB,16) f32
    const float* __restrict__ cp,    // (N_VOX,3) f32
    const int*   __restrict__ c2c,   // (N_VOX,8) i32
    const float* __restrict__ vox,   // (1,) f32
    float*       __restrict__ out,   // (N,16) f32
    int N)
{
    const int t = blockIdx.x * blockDim.x + threadIdx.x;
    const int n = t >> 2;        // point index
    const int q = t & 3;         // 4-dim chunk index
    if (n >= N) return;

    const int v = p2v[n];

    // 8 corner embedding indices (same for the 4 lanes of this point; L1 broadcast)
    const int4* c4 = (const int4*)(c2c + 8 * (size_t)v);
    const int4 ci0 = c4[0];
    const int4 ci1 = c4[1];
    const int cidx[8] = {ci0.x, ci0.y, ci0.z, ci0.w, ci1.x, ci1.y, ci1.z, ci1.w};

    // Issue all 8 gathers up-front (independent -> 8 outstanding dwordx4/lane)
    v4f e[8];
    #pragma unroll
    for (int c = 0; c < 8; ++c) {
        e[c] = *(const v4f*)(emb + 16 * (size_t)cidx[c] + 4 * q);
    }

    // Trilinear weights (redundant across the 4 lanes; VALU is nearly idle)
    const float inv_vs = 1.0f / vox[0];
    const float* pp  = pts + 3 * (size_t)n;
    const float* cpp = cp  + 3 * (size_t)v;
    const float px = (pp[0] - cpp[0]) * inv_vs + 0.5f;
    const float py = (pp[1] - cpp[1]) * inv_vs + 0.5f;
    const float pz = (pp[2] - cpp[2]) * inv_vs + 0.5f;
    const float wx[2] = {1.0f - px, px};
    const float wy[2] = {1.0f - py, py};
    const float wz[2] = {1.0f - pz, pz};

    v4f acc = (v4f)(0.0f);
    #pragma unroll
    for (int c = 0; c < 8; ++c) {
        const float w = wx[(c >> 2) & 1] * wy[(c >> 1) & 1] * wz[c & 1];
        acc.x = fmaf(w, e[c].x, acc.x);
        acc.y = fmaf(w, e[c].y, acc.y);
        acc.z = fmaf(w, e[c].z, acc.z);
        acc.w = fmaf(w, e[c].w, acc.w);
    }

    // lane t stores out[4t .. 4t+3] -> perfectly coalesced; nontemporal (write-only stream)
    __builtin_nontemporal_store(acc, (v4f*)(out + 4 * (size_t)t));
}

extern "C" void kernel_launch(void* const* d_in, const int* in_sizes, int n_in,
                              void* d_out, int out_size, void* d_ws, size_t ws_size,
                              hipStream_t stream) {
    const float* pts = (const float*)d_in[0];
    const int*   p2v = (const int*)d_in[1];
    const float* emb = (const float*)d_in[2];
    const float* cp  = (const float*)d_in[3];
    const int*   c2c = (const int*)d_in[4];
    const float* vox = (const float*)d_in[5];
    float*       out = (float*)d_out;

    const int N = in_sizes[1];  // N_PTS = 2,000,000
    const int block = 256;
    const long long threads = 4LL * N;
    const int grid = (int)((threads + block - 1) / block);
    VoxelEncoding_kernel<<<grid, block, 0, stream>>>(pts, p2v, emb, cp, c2c, vox, out, N);
}

// Round 5
// 527.598 us; speedup vs baseline: 1.0191x; 1.0191x over previous
//
#include <hip/hip_runtime.h>
#include <hip/hip_bf16.h>

// VoxelEncoding via counting-sort by voxel id:
//   K0 zero hist -> K1 histogram(p2v) -> K2 block scan -> K3 scan block sums
//   -> K4 add offsets -> K5 scatter {xyz,orig} to sorted order
//   -> K6 main: 4 lanes/point in sorted order (same-voxel points adjacent ->
//      duplicate embedding gathers merge in TA/L1; c2c/cp reads near-sequential),
//      output scattered back to orig rows (64-B aligned lines, no amplification).

typedef float v4f __attribute__((ext_vector_type(4)));

// ---------------- K0: zero histogram ----------------
__global__ void k_zero(unsigned* __restrict__ hist, int n) {
    int i = blockIdx.x * blockDim.x + threadIdx.x;
    if (i < n) hist[i] = 0u;
}

// ---------------- K1: histogram ----------------
__global__ void k_hist(const int* __restrict__ p2v, unsigned* __restrict__ hist, int N) {
    int i = blockIdx.x * blockDim.x + threadIdx.x;
    if (i < N) atomicAdd(&hist[p2v[i]], 1u);
}

// ---------------- K2: per-block exclusive scan (1024 bins/block) ----------------
__global__ __launch_bounds__(256) void k_scan_blocks(unsigned* __restrict__ hist,
                                                     unsigned* __restrict__ bsums, int nbins) {
    __shared__ unsigned tsum[256];
    const int tid = threadIdx.x;
    const int i0 = blockIdx.x * 1024 + tid * 4;
    unsigned v[4]; unsigned s = 0;
    #pragma unroll
    for (int k = 0; k < 4; ++k) {
        unsigned c = (i0 + k < nbins) ? hist[i0 + k] : 0u;
        v[k] = s; s += c;
    }
    tsum[tid] = s; __syncthreads();
    for (int off = 1; off < 256; off <<= 1) {
        unsigned x = tsum[tid];
        unsigned y = (tid >= off) ? tsum[tid - off] : 0u;
        __syncthreads();
        tsum[tid] = x + y;
        __syncthreads();
    }
    unsigned prefix = (tid > 0) ? tsum[tid - 1] : 0u;
    #pragma unroll
    for (int k = 0; k < 4; ++k) {
        if (i0 + k < nbins) hist[i0 + k] = prefix + v[k];
    }
    if (tid == 255) bsums[blockIdx.x] = tsum[255];
}

// ---------------- K3: exclusive scan of block sums (single block, nb <= 1024) ----------------
__global__ __launch_bounds__(256) void k_scan_sums(unsigned* __restrict__ bsums, int nb) {
    __shared__ unsigned tsum[256];
    const int tid = threadIdx.x;
    const int i0 = tid * 4;
    unsigned v[4]; unsigned s = 0;
    #pragma unroll
    for (int k = 0; k < 4; ++k) {
        unsigned c = (i0 + k < nb) ? bsums[i0 + k] : 0u;
        v[k] = s; s += c;
    }
    tsum[tid] = s; __syncthreads();
    for (int off = 1; off < 256; off <<= 1) {
        unsigned x = tsum[tid];
        unsigned y = (tid >= off) ? tsum[tid - off] : 0u;
        __syncthreads();
        tsum[tid] = x + y;
        __syncthreads();
    }
    unsigned prefix = (tid > 0) ? tsum[tid - 1] : 0u;
    #pragma unroll
    for (int k = 0; k < 4; ++k) {
        if (i0 + k < nb) bsums[i0 + k] = prefix + v[k];
    }
}

// ---------------- K4: add block offsets -> global exclusive offsets ----------------
__global__ void k_add(unsigned* __restrict__ hist, const unsigned* __restrict__ bsums, int nbins) {
    int i = blockIdx.x * blockDim.x + threadIdx.x;
    if (i < nbins) hist[i] += bsums[i >> 10];
}

// ---------------- K5: scatter points to sorted order ----------------
__global__ void k_scatter(const float* __restrict__ pts, const int* __restrict__ p2v,
                          unsigned* __restrict__ hist, unsigned* __restrict__ vsort,
                          v4f* __restrict__ rec, int N) {
    int i = blockIdx.x * blockDim.x + threadIdx.x;
    if (i >= N) return;
    const int v = p2v[i];
    const unsigned pos = atomicAdd(&hist[v], 1u);
    vsort[pos] = (unsigned)v;
    v4f r;
    r.x = pts[3 * (size_t)i];
    r.y = pts[3 * (size_t)i + 1];
    r.z = pts[3 * (size_t)i + 2];
    r.w = __int_as_float(i);
    rec[pos] = r;
}

// ---------------- K6: main interpolation over sorted points ----------------
__global__ __launch_bounds__(256) void k_main(
    const unsigned* __restrict__ vsort, const v4f* __restrict__ rec,
    const float* __restrict__ emb,   // (N_EMB,16)
    const float* __restrict__ cp,    // (N_VOX,3)
    const int*   __restrict__ c2c,   // (N_VOX,8)
    const float* __restrict__ vox,
    float*       __restrict__ out,   // (N,16)
    int N)
{
    const int t = blockIdx.x * blockDim.x + threadIdx.x;
    const int n = t >> 2;        // sorted point index
    const int q = t & 3;         // 4-dim chunk
    if (n >= N) return;

    const unsigned v = vsort[n];
    const v4f r = rec[n];
    const int orig = __float_as_int(r.w);

    const int4* c4 = (const int4*)(c2c + 8 * (size_t)v);
    const int4 ci0 = c4[0];
    const int4 ci1 = c4[1];
    const int cidx[8] = {ci0.x, ci0.y, ci0.z, ci0.w, ci1.x, ci1.y, ci1.z, ci1.w};

    v4f e[8];
    #pragma unroll
    for (int c = 0; c < 8; ++c) {
        e[c] = *(const v4f*)(emb + 16 * (size_t)cidx[c] + 4 * q);
    }

    const float inv_vs = 1.0f / vox[0];
    const float* cpp = cp + 3 * (size_t)v;
    const float px = (r.x - cpp[0]) * inv_vs + 0.5f;
    const float py = (r.y - cpp[1]) * inv_vs + 0.5f;
    const float pz = (r.z - cpp[2]) * inv_vs + 0.5f;
    const float wx[2] = {1.0f - px, px};
    const float wy[2] = {1.0f - py, py};
    const float wz[2] = {1.0f - pz, pz};

    v4f acc = (v4f)(0.0f);
    #pragma unroll
    for (int c = 0; c < 8; ++c) {
        const float w = wx[(c >> 2) & 1] * wy[(c >> 1) & 1] * wz[c & 1];
        acc.x = fmaf(w, e[c].x, acc.x);
        acc.y = fmaf(w, e[c].y, acc.y);
        acc.z = fmaf(w, e[c].z, acc.z);
        acc.w = fmaf(w, e[c].w, acc.w);
    }

    __builtin_nontemporal_store(acc, (v4f*)(out + 16 * (size_t)orig + 4 * q));
}

// ---------------- fallback (no-sort direct), used only if ws too small ----------------
__global__ __launch_bounds__(256) void k_direct(
    const float* __restrict__ pts, const int* __restrict__ p2v,
    const float* __restrict__ emb, const float* __restrict__ cp,
    const int* __restrict__ c2c, const float* __restrict__ vox,
    float* __restrict__ out, int N)
{
    const int t = blockIdx.x * blockDim.x + threadIdx.x;
    const int n = t >> 2, q = t & 3;
    if (n >= N) return;
    const int v = p2v[n];
    const int4* c4 = (const int4*)(c2c + 8 * (size_t)v);
    const int4 ci0 = c4[0], ci1 = c4[1];
    const int cidx[8] = {ci0.x, ci0.y, ci0.z, ci0.w, ci1.x, ci1.y, ci1.z, ci1.w};
    v4f e[8];
    #pragma unroll
    for (int c = 0; c < 8; ++c) e[c] = *(const v4f*)(emb + 16 * (size_t)cidx[c] + 4 * q);
    const float inv_vs = 1.0f / vox[0];
    const float* pp = pts + 3 * (size_t)n;
    const float* cpp = cp + 3 * (size_t)v;
    const float px = (pp[0] - cpp[0]) * inv_vs + 0.5f;
    const float py = (pp[1] - cpp[1]) * inv_vs + 0.5f;
    const float pz = (pp[2] - cpp[2]) * inv_vs + 0.5f;
    const float wx[2] = {1.0f - px, px};
    const float wy[2] = {1.0f - py, py};
    const float wz[2] = {1.0f - pz, pz};
    v4f acc = (v4f)(0.0f);
    #pragma unroll
    for (int c = 0; c < 8; ++c) {
        const float w = wx[(c >> 2) & 1] * wy[(c >> 1) & 1] * wz[c & 1];
        acc.x = fmaf(w, e[c].x, acc.x); acc.y = fmaf(w, e[c].y, acc.y);
        acc.z = fmaf(w, e[c].z, acc.z); acc.w = fmaf(w, e[c].w, acc.w);
    }
    __builtin_nontemporal_store(acc, (v4f*)(out + 4 * (size_t)t));
}

extern "C" void kernel_launch(void* const* d_in, const int* in_sizes, int n_in,
                              void* d_out, int out_size, void* d_ws, size_t ws_size,
                              hipStream_t stream) {
    const float* pts = (const float*)d_in[0];
    const int*   p2v = (const int*)d_in[1];
    const float* emb = (const float*)d_in[2];
    const float* cp  = (const float*)d_in[3];
    const int*   c2c = (const int*)d_in[4];
    const float* vox = (const float*)d_in[5];
    float*       out = (float*)d_out;

    const int N  = in_sizes[1];       // 2,000,000 points
    const int NV = in_sizes[4] / 8;   // 500,000 voxels

    // workspace layout (bytes)
    const size_t off_hist  = 0;                        // NV * 4
    const size_t off_bsums = 2u * 1024u * 1024u;       // <=1024 * 4
    const size_t off_vsort = 4u * 1024u * 1024u;       // N * 4
    const size_t off_rec   = 16u * 1024u * 1024u;      // N * 16
    const size_t need = off_rec + (size_t)N * 16u;

    if (ws_size < need) {
        const int block = 256;
        const long long threads = 4LL * N;
        k_direct<<<(int)((threads + block - 1) / block), block, 0, stream>>>(
            pts, p2v, emb, cp, c2c, vox, out, N);
        return;
    }

    unsigned* hist  = (unsigned*)((char*)d_ws + off_hist);
    unsigned* bsums = (unsigned*)((char*)d_ws + off_bsums);
    unsigned* vsort = (unsigned*)((char*)d_ws + off_vsort);
    v4f*      rec   = (v4f*)((char*)d_ws + off_rec);

    const int block = 256;
    const int nscan = (NV + 1023) / 1024;   // 489 blocks; k_scan_sums handles <=1024

    k_zero<<<(NV + block - 1) / block, block, 0, stream>>>(hist, NV);
    k_hist<<<(N + block - 1) / block, block, 0, stream>>>(p2v, hist, N);
    k_scan_blocks<<<nscan, 256, 0, stream>>>(hist, bsums, NV);
    k_scan_sums<<<1, 256, 0, stream>>>(bsums, nscan);
    k_add<<<(NV + block - 1) / block, block, 0, stream>>>(hist, bsums, NV);
    k_scatter<<<(N + block - 1) / block, block, 0, stream>>>(pts, p2v, hist, vsort, rec, N);

    const long long threads = 4LL * N;
    k_main<<<(int)((threads + block - 1) / block), block, 0, stream>>>(
        vsort, rec, emb, cp, c2c, vox, out, N);
}